// Round 12
// baseline (1554.904 us; speedup 1.0000x reference)
//
#include <hip/hip_runtime.h>
#include <hip/hip_fp16.h>
#include <math.h>

#define NNODES 100000
#define NEDGES 1200000
#define HD 64
#define NLAYERS 8
#define NGRAPH 100
#define PPART 32          // pooling partitions per graph
#define C8 16777216.0f    // 8^8 = 2^24, exact in f32

// ---------- fp16 storage helpers (arithmetic stays f32) ----------
__device__ __forceinline__ float h2f(__half h) { return __half2float(h); }
__device__ __forceinline__ __half f2h(float f) { return __float2half(f); }  // RNE

// readlane: broadcast lane l's float to all lanes via SGPR (VALU pipe, no LDS)
__device__ __forceinline__ float rl(float v, int l) {
    return __uint_as_float(__builtin_amdgcn_readlane(__float_as_uint(v), l));
}

// ---------- lin0: x0 = relu(pos @ lin0_w + lin0_b), f32 + fp16 copies ----------
__global__ void lin0_k(const float* __restrict__ pos, const float* __restrict__ w,
                       const float* __restrict__ b, float* __restrict__ x0f,
                       __half* __restrict__ x0h, int total) {
    int i = blockIdx.x * blockDim.x + threadIdx.x;
    if (i >= total) return;
    int n = i >> 6, h = i & 63;
    float p0 = pos[n * 3 + 0], p1 = pos[n * 3 + 1], p2 = pos[n * 3 + 2];
    float v = fmaf(p0, w[h], fmaf(p1, w[64 + h], fmaf(p2, w[128 + h], b[h])));
    v = fmaxf(v, 0.0f);
    x0f[i] = v;
    x0h[i] = f2h(v);      // layer-0 input, scale c_0 = 1
}

// ---------- CSR build ----------
__global__ void hist_k(const int* __restrict__ dst, int* __restrict__ deg,
                       int* __restrict__ rank, int E) {
    int e = blockIdx.x * blockDim.x + threadIdx.x;
    if (e < E) rank[e] = atomicAdd(&deg[dst[e]], 1);
}

__global__ void scan_part_k(const int* __restrict__ deg, int* __restrict__ bsum, int n) {
    __shared__ int s[256];
    int t = threadIdx.x;
    int i = blockIdx.x * 256 + t;
    s[t] = (i < n) ? deg[i] : 0;
    __syncthreads();
    for (int off = 128; off > 0; off >>= 1) {
        if (t < off) s[t] += s[t + off];
        __syncthreads();
    }
    if (t == 0) bsum[blockIdx.x] = s[0];
}

__global__ void scan_mid_k(const int* __restrict__ bsum, int* __restrict__ boff,
                           int nblk, int* __restrict__ roff, int n) {
    __shared__ int s[512];
    int t = threadIdx.x;
    int v = (t < nblk) ? bsum[t] : 0;
    s[t] = v;
    __syncthreads();
    for (int off = 1; off < 512; off <<= 1) {
        int u = (t >= off) ? s[t - off] : 0;
        __syncthreads();
        s[t] += u;
        __syncthreads();
    }
    if (t < nblk) boff[t] = s[t] - v;          // exclusive
    if (t == nblk - 1) roff[n] = s[t];         // == E
}

__global__ void scan_final_k(const int* __restrict__ deg, const int* __restrict__ boff,
                             int* __restrict__ roff, int n) {
    __shared__ int s[256];
    int t = threadIdx.x;
    int i = blockIdx.x * 256 + t;
    int v = (i < n) ? deg[i] : 0;
    s[t] = v;
    __syncthreads();
    for (int off = 1; off < 256; off <<= 1) {
        int u = (t >= off) ? s[t - off] : 0;
        __syncthreads();
        s[t] += u;
        __syncthreads();
    }
    if (i < n) roff[i] = boff[blockIdx.x] + s[t] - v;   // exclusive scan
}

// pure permute-write, no atomic (rank precomputed in hist_k)
__global__ void fill_k(const int* __restrict__ src, const int* __restrict__ dst,
                       const int* __restrict__ roff, const int* __restrict__ rank,
                       int* __restrict__ csr, int E) {
    int e = blockIdx.x * blockDim.x + threadIdx.x;
    if (e < E) csr[roff[dst[e]] + rank[e]] = src[e];
}

// ---------- fused GCN2 layer: agg + residual + GEMM + relu ----------
// One wave per node (round-9 proven gather structure). M_folded =
// (1/8)*((1-beta)*I + beta*W) in LDS as swizzled M^T (conflict-free
// ds_read_b128). h broadcast via v_readlane with compile-time lane index
// (VALU pipe) -- eliminates the hrow LDS round-trip, cutting LDS ops/node
// from 33 (63.5us measured, model-confirmed) to 16 (~32us predicted).
// Multi-node batching is NOT used: both 4-node and 2-node variants spilled
// (compiler interleaves gather bodies; live-set doubles -> scratch).
__global__ __launch_bounds__(256, 8) void layer_k(
    const __half* __restrict__ xin, __half* __restrict__ xout,
    const float* __restrict__ x0, const float* __restrict__ W,
    const int* __restrict__ roff, const int* __restrict__ csr,
    float beta, float x0scale, int total_waves) {
    __shared__ __align__(16) float MT[64 * 64];
    const int tid  = threadIdx.x;
    const int lane = tid & 63;
    const float omb = 1.0f - beta;
    for (int idx = tid; idx < 4096; idx += 256) {
        int k = idx >> 6, j = idx & 63;
        float m = beta * W[idx];
        if (k == j) m += omb;
        m *= 0.125f;                           // fold r = 1/8 (exact)
        MT[j * 64 + (((k >> 2) ^ (j & 15)) << 2) + (k & 3)] = m;
    }
    __syncthreads();
    const int wid0 = (blockIdx.x * blockDim.x + tid) >> 6;
    for (int n = wid0; n < NNODES; n += total_waves) {
        const int beg = roff[n], end = roff[n + 1];
        float x0v = x0[(n << 6) + lane];      // issue early, overlaps gather
        float s0 = 0.0f, s1 = 0.0f, s2 = 0.0f, s3 = 0.0f;
        int i = beg;
        for (; i + 8 <= end; i += 8) {
            int e0 = csr[i + 0], e1 = csr[i + 1], e2 = csr[i + 2], e3 = csr[i + 3];
            int e4 = csr[i + 4], e5 = csr[i + 5], e6 = csr[i + 6], e7 = csr[i + 7];
            __half b0 = xin[(e0 << 6) + lane];
            __half b1 = xin[(e1 << 6) + lane];
            __half b2 = xin[(e2 << 6) + lane];
            __half b3 = xin[(e3 << 6) + lane];
            __half b4 = xin[(e4 << 6) + lane];
            __half b5 = xin[(e5 << 6) + lane];
            __half b6 = xin[(e6 << 6) + lane];
            __half b7 = xin[(e7 << 6) + lane];
            s0 += h2f(b0); s1 += h2f(b1); s2 += h2f(b2); s3 += h2f(b3);
            s0 += h2f(b4); s1 += h2f(b5); s2 += h2f(b6); s3 += h2f(b7);
        }
        for (; i + 4 <= end; i += 4) {
            int e0 = csr[i + 0], e1 = csr[i + 1], e2 = csr[i + 2], e3 = csr[i + 3];
            s0 += h2f(xin[(e0 << 6) + lane]);
            s1 += h2f(xin[(e1 << 6) + lane]);
            s2 += h2f(xin[(e2 << 6) + lane]);
            s3 += h2f(xin[(e3 << 6) + lane]);
        }
        for (; i < end; ++i) s0 += h2f(xin[(csr[i] << 6) + lane]);
        float h = fmaf(0.9f, (s0 + s1) + (s2 + s3), x0scale * x0v);
        // ---- MLP: o[lane] = sum_k h[k] * M[k][lane], h via readlane ----
        float a0 = 0.0f, a1 = 0.0f, a2 = 0.0f, a3 = 0.0f;
#pragma unroll
        for (int g = 0; g < 16; ++g) {
            float4 mv = *(const float4*)&MT[(lane << 6) + ((g ^ (lane & 15)) << 2)];
            a0 = fmaf(rl(h, 4 * g + 0), mv.x, a0);
            a1 = fmaf(rl(h, 4 * g + 1), mv.y, a1);
            a2 = fmaf(rl(h, 4 * g + 2), mv.z, a2);
            a3 = fmaf(rl(h, 4 * g + 3), mv.w, a3);
        }
        float o = (a0 + a1) + (a2 + a3);   // identity + r already folded into M
        xout[(n << 6) + lane] = f2h(fmaxf(o, 0.0f));
    }
}

// ---------- lin1 + segment_max pooling, ZERO atomics, 32 partitions ----------
__device__ __forceinline__ int lbound(const int* __restrict__ a, int n, int v) {
    int lo = 0, hi = n;
    while (lo < hi) { int mid = (lo + hi) >> 1; if (a[mid] < v) lo = mid + 1; else hi = mid; }
    return lo;
}

__global__ __launch_bounds__(256, 8) void poolpart_k(
    const __half* __restrict__ xin, const float* __restrict__ W,
    const float* __restrict__ bvec, const int* __restrict__ batch,
    float* __restrict__ pmax) {
    __shared__ __align__(16) float MT[64 * 64];
    __shared__ float wm[4][64];
    const int tid   = threadIdx.x;
    const int lane  = tid & 63;
    const int wslot = tid >> 6;
    for (int idx = tid; idx < 4096; idx += 256) {
        int k = idx >> 6, j = idx & 63;
        MT[j * 64 + (((k >> 2) ^ (j & 15)) << 2) + (k & 3)] = W[idx];
    }
    __syncthreads();
    const int g = blockIdx.x / PPART, part = blockIdx.x % PPART;
    const int lo = lbound(batch, NNODES, g);
    const int hi = lbound(batch, NNODES, g + 1);
    const int cnt = hi - lo;
    const int qlo = lo + (cnt * part) / PPART;
    const int qhi = lo + (cnt * (part + 1)) / PPART;
    const float bias = bvec[lane];
    float vmax = -INFINITY;
    for (int n = qlo + wslot; n < qhi; n += 4) {
        float h = h2f(xin[(n << 6) + lane]);   // stored units (x/8^8)
        float a0 = 0.0f, a1 = 0.0f, a2 = 0.0f, a3 = 0.0f;
#pragma unroll
        for (int gg = 0; gg < 16; ++gg) {
            float4 mv = *(const float4*)&MT[(lane << 6) + ((gg ^ (lane & 15)) << 2)];
            a0 = fmaf(rl(h, 4 * gg + 0), mv.x, a0);
            a1 = fmaf(rl(h, 4 * gg + 1), mv.y, a1);
            a2 = fmaf(rl(h, 4 * gg + 2), mv.z, a2);
            a3 = fmaf(rl(h, 4 * gg + 3), mv.w, a3);
        }
        float acc = (a0 + a1) + (a2 + a3);
        vmax = fmaxf(vmax, fmaf(C8, acc, bias));         // undo 8^8 scale (exact 2^24)
    }
    wm[wslot][lane] = vmax;
    __syncthreads();
    if (tid < 64) {
        float m = fmaxf(fmaxf(wm[0][tid], wm[1][tid]), fmaxf(wm[2][tid], wm[3][tid]));
        pmax[blockIdx.x * 64 + tid] = m;
    }
}

__global__ void poolcomb_k(const float* __restrict__ pmax, float* __restrict__ pooled) {
    int i = blockIdx.x * blockDim.x + threadIdx.x;
    if (i >= NGRAPH * 64) return;
    int g = i >> 6, lane = i & 63;
    float m = -INFINITY;
    for (int p = 0; p < PPART; ++p)
        m = fmaxf(m, pmax[(PPART * g + p) * 64 + lane]);
    pooled[i] = m;   // may be -inf for empty graphs; head guards
}

// ---------- head: MLP + BN + out + log_softmax, single block ----------
__global__ __launch_bounds__(256) void head_k(
    const float* __restrict__ pooled,
    const float* __restrict__ m1w, const float* __restrict__ m1b,
    const float* __restrict__ g1, const float* __restrict__ be1,
    const float* __restrict__ m2w, const float* __restrict__ m2b,
    const float* __restrict__ g2, const float* __restrict__ be2,
    const float* __restrict__ ow, const float* __restrict__ ob,
    float* __restrict__ out) {
    __shared__ float A[NGRAPH * 64];
    __shared__ float B[NGRAPH * 64];
    __shared__ float mu[64], rs[64];
    __shared__ float LG[NGRAPH * 10];
    int t = threadIdx.x;
    for (int i = t; i < NGRAPH * 64; i += 256) {
        float f = pooled[i];
        if (!isfinite(f)) f = 0.0f;   // empty-segment guard
        A[i] = f;
    }
    __syncthreads();
    // ---- mlp1 ----
    for (int i = t; i < NGRAPH * 64; i += 256) {
        int g = i >> 6, j = i & 63;
        float acc = m1b[j];
        for (int k = 0; k < 64; ++k) acc = fmaf(A[(g << 6) + k], m1w[k * 64 + j], acc);
        B[i] = acc;
    }
    __syncthreads();
    if (t < 64) {
        float sm = 0.0f, sq = 0.0f;
        for (int g = 0; g < NGRAPH; ++g) { float z = B[g * 64 + t]; sm += z; sq += z * z; }
        float m = sm * (1.0f / NGRAPH);
        float var = sq * (1.0f / NGRAPH) - m * m;
        mu[t] = m; rs[t] = rsqrtf(var + 1e-5f);
    }
    __syncthreads();
    for (int i = t; i < NGRAPH * 64; i += 256) {
        int j = i & 63;
        float z = fmaf((B[i] - mu[j]) * rs[j], g1[j], be1[j]);
        A[i] = fmaxf(z, 0.0f);
    }
    __syncthreads();
    // ---- mlp2 ----
    for (int i = t; i < NGRAPH * 64; i += 256) {
        int g = i >> 6, j = i & 63;
        float acc = m2b[j];
        for (int k = 0; k < 64; ++k) acc = fmaf(A[(g << 6) + k], m2w[k * 64 + j], acc);
        B[i] = acc;
    }
    __syncthreads();
    if (t < 64) {
        float sm = 0.0f, sq = 0.0f;
        for (int g = 0; g < NGRAPH; ++g) { float z = B[g * 64 + t]; sm += z; sq += z * z; }
        float m = sm * (1.0f / NGRAPH);
        float var = sq * (1.0f / NGRAPH) - m * m;
        mu[t] = m; rs[t] = rsqrtf(var + 1e-5f);
    }
    __syncthreads();
    for (int i = t; i < NGRAPH * 64; i += 256) {
        int j = i & 63;
        float z = fmaf((B[i] - mu[j]) * rs[j], g2[j], be2[j]);
        A[i] = fmaxf(z, 0.0f);
    }
    __syncthreads();
    // ---- out + log_softmax ----
    for (int i = t; i < NGRAPH * 10; i += 256) {
        int g = i / 10, j = i - g * 10;
        float acc = ob[j];
        for (int k = 0; k < 64; ++k) acc = fmaf(A[(g << 6) + k], ow[k * 10 + j], acc);
        LG[i] = acc;
    }
    __syncthreads();
    if (t < NGRAPH) {
        float m = -1e30f;
        for (int j = 0; j < 10; ++j) m = fmaxf(m, LG[t * 10 + j]);
        float s = 0.0f;
        for (int j = 0; j < 10; ++j) s += expf(LG[t * 10 + j] - m);
        float lse = m + logf(s);
        for (int j = 0; j < 10; ++j) out[t * 10 + j] = LG[t * 10 + j] - lse;
    }
}

extern "C" void kernel_launch(void* const* d_in, const int* in_sizes, int n_in,
                              void* d_out, int out_size, void* d_ws, size_t ws_size,
                              hipStream_t stream) {
    const float* pos   = (const float*)d_in[0];
    const int*   eidx  = (const int*)d_in[1];
    const int*   batch = (const int*)d_in[2];
    const float* l0w   = (const float*)d_in[3];
    const float* l0b   = (const float*)d_in[4];
    const float* cw    = (const float*)d_in[5];
    const float* l1w   = (const float*)d_in[6];
    const float* l1b   = (const float*)d_in[7];
    const float* m1w   = (const float*)d_in[8];
    const float* m1b   = (const float*)d_in[9];
    const float* g1    = (const float*)d_in[10];
    const float* b1    = (const float*)d_in[11];
    const float* m2w   = (const float*)d_in[12];
    const float* m2b   = (const float*)d_in[13];
    const float* g2    = (const float*)d_in[14];
    const float* b2    = (const float*)d_in[15];
    const float* ow    = (const float*)d_in[16];
    const float* ob    = (const float*)d_in[17];
    float* out = (float*)d_out;
    const int* src = eidx;
    const int* dst = eidx + NEDGES;

    size_t off = 0;
    auto alloc = [&](size_t bytes) -> void* {
        void* p = (char*)d_ws + off;
        off += (bytes + 255) & ~(size_t)255;
        return p;
    };
    float*  x0f    = (float*)alloc((size_t)NNODES * 64 * 4);
    __half* x0h    = (__half*)alloc((size_t)NNODES * 64 * 2);
    __half* xA     = (__half*)alloc((size_t)NNODES * 64 * 2);
    __half* xB     = (__half*)alloc((size_t)NNODES * 64 * 2);
    int*    deg    = (int*)alloc((size_t)NNODES * 4);
    int*    roff   = (int*)alloc((size_t)(NNODES + 1) * 4);
    const int NBLK = (NNODES + 255) / 256;                     // 391
    int*    bsum   = (int*)alloc((size_t)NBLK * 4);
    int*    boff   = (int*)alloc((size_t)NBLK * 4);
    int*    csr    = (int*)alloc((size_t)NEDGES * 4);
    float*  pooled = (float*)alloc((size_t)NGRAPH * 64 * 4);
    float*  pmax   = (float*)alloc((size_t)NGRAPH * PPART * 64 * 4);
    int*    rank   = (int*)xB;   // xB (12.8MB) dead until layer 1 writes it

    hipMemsetAsync(deg, 0, (size_t)NNODES * 4, stream);
    {
        int total = NNODES * 64;
        lin0_k<<<(total + 255) / 256, 256, 0, stream>>>(pos, l0w, l0b, x0f, x0h, total);
    }
    hist_k<<<(NEDGES + 255) / 256, 256, 0, stream>>>(dst, deg, rank, NEDGES);
    scan_part_k<<<NBLK, 256, 0, stream>>>(deg, bsum, NNODES);
    scan_mid_k<<<1, 512, 0, stream>>>(bsum, boff, NBLK, roff, NNODES);
    scan_final_k<<<NBLK, 256, 0, stream>>>(deg, boff, roff, NNODES);
    fill_k<<<(NEDGES + 255) / 256, 256, 0, stream>>>(src, dst, roff, rank, csr, NEDGES);

    const int LBLOCKS = 2048;
    const int TW = LBLOCKS * 256 / 64;   // total waves = 8192
    const __half* cur = x0h;
    for (int l = 0; l < NLAYERS; ++l) {
        float beta    = (float)log(0.5 / (double)(l + 1) + 1.0);
        float x0scale = (float)(0.1 * ldexp(1.0, -3 * l));   // 0.1 / 8^l, exact scale chain
        __half* nxt = (l & 1) ? xB : xA;
        layer_k<<<LBLOCKS, 256, 0, stream>>>(cur, nxt, x0f, cw + (size_t)l * 4096,
                                             roff, csr, beta, x0scale, TW);
        cur = nxt;
    }
    poolpart_k<<<NGRAPH * PPART, 256, 0, stream>>>(cur, l1w, l1b, batch, pmax);
    poolcomb_k<<<(NGRAPH * 64 + 255) / 256, 256, 0, stream>>>(pmax, pooled);
    head_k<<<1, 256, 0, stream>>>(pooled, m1w, m1b, g1, b1, m2w, m2b, g2, b2, ow, ob, out);
}

// Round 13
// 769.829 us; speedup vs baseline: 2.0198x; 2.0198x over previous
//
#include <hip/hip_runtime.h>
#include <hip/hip_fp16.h>
#include <math.h>

#define NNODES 100000
#define NEDGES 1200000
#define HD 64
#define NLAYERS 8
#define NGRAPH 100
#define PPART 32          // pooling partitions per graph
#define C8 16777216.0f    // 8^8 = 2^24, exact in f32

// ---------- fp16 storage helpers (arithmetic stays f32) ----------
__device__ __forceinline__ float h2f(__half h) { return __half2float(h); }
__device__ __forceinline__ __half f2h(float f) { return __float2half(f); }  // RNE

// readlane with RUNTIME lane index (SGPR): cannot be hoisted ahead of the loop
__device__ __forceinline__ float rld(float v, int l) {
    return __uint_as_float(__builtin_amdgcn_readlane(__float_as_uint(v), l));
}

// ---------- lin0: x0 = relu(pos @ lin0_w + lin0_b), f32 + fp16 copies ----------
__global__ void lin0_k(const float* __restrict__ pos, const float* __restrict__ w,
                       const float* __restrict__ b, float* __restrict__ x0f,
                       __half* __restrict__ x0h, int total) {
    int i = blockIdx.x * blockDim.x + threadIdx.x;
    if (i >= total) return;
    int n = i >> 6, h = i & 63;
    float p0 = pos[n * 3 + 0], p1 = pos[n * 3 + 1], p2 = pos[n * 3 + 2];
    float v = fmaf(p0, w[h], fmaf(p1, w[64 + h], fmaf(p2, w[128 + h], b[h])));
    v = fmaxf(v, 0.0f);
    x0f[i] = v;
    x0h[i] = f2h(v);      // layer-0 input, scale c_0 = 1
}

// ---------- CSR build ----------
__global__ void hist_k(const int* __restrict__ dst, int* __restrict__ deg,
                       int* __restrict__ rank, int E) {
    int e = blockIdx.x * blockDim.x + threadIdx.x;
    if (e < E) rank[e] = atomicAdd(&deg[dst[e]], 1);
}

__global__ void scan_part_k(const int* __restrict__ deg, int* __restrict__ bsum, int n) {
    __shared__ int s[256];
    int t = threadIdx.x;
    int i = blockIdx.x * 256 + t;
    s[t] = (i < n) ? deg[i] : 0;
    __syncthreads();
    for (int off = 128; off > 0; off >>= 1) {
        if (t < off) s[t] += s[t + off];
        __syncthreads();
    }
    if (t == 0) bsum[blockIdx.x] = s[0];
}

__global__ void scan_mid_k(const int* __restrict__ bsum, int* __restrict__ boff,
                           int nblk, int* __restrict__ roff, int n) {
    __shared__ int s[512];
    int t = threadIdx.x;
    int v = (t < nblk) ? bsum[t] : 0;
    s[t] = v;
    __syncthreads();
    for (int off = 1; off < 512; off <<= 1) {
        int u = (t >= off) ? s[t - off] : 0;
        __syncthreads();
        s[t] += u;
        __syncthreads();
    }
    if (t < nblk) boff[t] = s[t] - v;          // exclusive
    if (t == nblk - 1) roff[n] = s[t];         // == E
}

__global__ void scan_final_k(const int* __restrict__ deg, const int* __restrict__ boff,
                             int* __restrict__ roff, int n) {
    __shared__ int s[256];
    int t = threadIdx.x;
    int i = blockIdx.x * 256 + t;
    int v = (i < n) ? deg[i] : 0;
    s[t] = v;
    __syncthreads();
    for (int off = 1; off < 256; off <<= 1) {
        int u = (t >= off) ? s[t - off] : 0;
        __syncthreads();
        s[t] += u;
        __syncthreads();
    }
    if (i < n) roff[i] = boff[blockIdx.x] + s[t] - v;   // exclusive scan
}

// pure permute-write, no atomic (rank precomputed in hist_k)
__global__ void fill_k(const int* __restrict__ src, const int* __restrict__ dst,
                       const int* __restrict__ roff, const int* __restrict__ rank,
                       int* __restrict__ csr, int E) {
    int e = blockIdx.x * blockDim.x + threadIdx.x;
    if (e < E) csr[roff[dst[e]] + rank[e]] = src[e];
}

// ---------- fused GCN2 layer: agg + residual + GEMM + relu ----------
// One wave per node (round-9 proven gather structure). M_folded =
// (1/8)*((1-beta)*I + beta*W) in LDS as swizzled M^T (conflict-free
// ds_read_b128). h broadcast via v_readlane with RUNTIME (SGPR) lane
// index inside a ROLLED loop (#pragma unroll 1): the readlanes cannot
// be hoisted, so the live-set stays ~35 VGPRs (unrolled variants with
// hoistable readlanes/gathers all spilled: FETCH 222-539 MB, r10-r12).
// LDS ops/node: 17 vs 33 (hrow round-trip eliminated) -> ~31us model.
__global__ __launch_bounds__(256, 8) void layer_k(
    const __half* __restrict__ xin, __half* __restrict__ xout,
    const float* __restrict__ x0, const float* __restrict__ W,
    const int* __restrict__ roff, const int* __restrict__ csr,
    float beta, float x0scale, int total_waves) {
    __shared__ __align__(16) float MT[64 * 64];
    const int tid  = threadIdx.x;
    const int lane = tid & 63;
    const float omb = 1.0f - beta;
    for (int idx = tid; idx < 4096; idx += 256) {
        int k = idx >> 6, j = idx & 63;
        float m = beta * W[idx];
        if (k == j) m += omb;
        m *= 0.125f;                           // fold r = 1/8 (exact)
        MT[j * 64 + (((k >> 2) ^ (j & 15)) << 2) + (k & 3)] = m;
    }
    __syncthreads();
    const int wid0 = (blockIdx.x * blockDim.x + tid) >> 6;
    for (int n = wid0; n < NNODES; n += total_waves) {
        const int beg = roff[n], end = roff[n + 1];
        float x0v = x0[(n << 6) + lane];      // issue early, overlaps gather
        float s0 = 0.0f, s1 = 0.0f, s2 = 0.0f, s3 = 0.0f;
        int i = beg;
        for (; i + 8 <= end; i += 8) {
            int e0 = csr[i + 0], e1 = csr[i + 1], e2 = csr[i + 2], e3 = csr[i + 3];
            int e4 = csr[i + 4], e5 = csr[i + 5], e6 = csr[i + 6], e7 = csr[i + 7];
            __half b0 = xin[(e0 << 6) + lane];
            __half b1 = xin[(e1 << 6) + lane];
            __half b2 = xin[(e2 << 6) + lane];
            __half b3 = xin[(e3 << 6) + lane];
            __half b4 = xin[(e4 << 6) + lane];
            __half b5 = xin[(e5 << 6) + lane];
            __half b6 = xin[(e6 << 6) + lane];
            __half b7 = xin[(e7 << 6) + lane];
            s0 += h2f(b0); s1 += h2f(b1); s2 += h2f(b2); s3 += h2f(b3);
            s0 += h2f(b4); s1 += h2f(b5); s2 += h2f(b6); s3 += h2f(b7);
        }
        for (; i + 4 <= end; i += 4) {
            int e0 = csr[i + 0], e1 = csr[i + 1], e2 = csr[i + 2], e3 = csr[i + 3];
            s0 += h2f(xin[(e0 << 6) + lane]);
            s1 += h2f(xin[(e1 << 6) + lane]);
            s2 += h2f(xin[(e2 << 6) + lane]);
            s3 += h2f(xin[(e3 << 6) + lane]);
        }
        for (; i < end; ++i) s0 += h2f(xin[(csr[i] << 6) + lane]);
        float h = fmaf(0.9f, (s0 + s1) + (s2 + s3), x0scale * x0v);
        // ---- MLP: o[lane] = sum_k h[k]*M[k][lane]; rolled, runtime readlane ----
        float a0 = 0.0f, a1 = 0.0f, a2 = 0.0f, a3 = 0.0f;
#pragma unroll 1
        for (int g = 0; g < 16; ++g) {
            float4 mv = *(const float4*)&MT[(lane << 6) + ((g ^ (lane & 15)) << 2)];
            a0 = fmaf(rld(h, 4 * g + 0), mv.x, a0);
            a1 = fmaf(rld(h, 4 * g + 1), mv.y, a1);
            a2 = fmaf(rld(h, 4 * g + 2), mv.z, a2);
            a3 = fmaf(rld(h, 4 * g + 3), mv.w, a3);
        }
        float o = (a0 + a1) + (a2 + a3);   // identity + r already folded into M
        xout[(n << 6) + lane] = f2h(fmaxf(o, 0.0f));
    }
}

// ---------- lin1 + segment_max pooling, ZERO atomics, 32 partitions ----------
// (round-9 proven hrow-broadcast form; ~10us aggregate, not worth risk)
__device__ __forceinline__ int lbound(const int* __restrict__ a, int n, int v) {
    int lo = 0, hi = n;
    while (lo < hi) { int mid = (lo + hi) >> 1; if (a[mid] < v) lo = mid + 1; else hi = mid; }
    return lo;
}

__global__ __launch_bounds__(256, 8) void poolpart_k(
    const __half* __restrict__ xin, const float* __restrict__ W,
    const float* __restrict__ bvec, const int* __restrict__ batch,
    float* __restrict__ pmax) {
    __shared__ __align__(16) float MT[64 * 64];
    __shared__ __align__(16) float hrow[4][64];
    __shared__ float wm[4][64];
    const int tid   = threadIdx.x;
    const int lane  = tid & 63;
    const int wslot = tid >> 6;
    for (int idx = tid; idx < 4096; idx += 256) {
        int k = idx >> 6, j = idx & 63;
        MT[j * 64 + (((k >> 2) ^ (j & 15)) << 2) + (k & 3)] = W[idx];
    }
    __syncthreads();
    const int g = blockIdx.x / PPART, part = blockIdx.x % PPART;
    const int lo = lbound(batch, NNODES, g);
    const int hi = lbound(batch, NNODES, g + 1);
    const int cnt = hi - lo;
    const int qlo = lo + (cnt * part) / PPART;
    const int qhi = lo + (cnt * (part + 1)) / PPART;
    const float bias = bvec[lane];
    float vmax = -INFINITY;
    for (int n = qlo + wslot; n < qhi; n += 4) {
        hrow[wslot][lane] = h2f(xin[(n << 6) + lane]);   // stored units (x/8^8)
        __builtin_amdgcn_wave_barrier();
        float a0 = 0.0f, a1 = 0.0f, a2 = 0.0f, a3 = 0.0f;
#pragma unroll
        for (int gg = 0; gg < 16; ++gg) {
            float4 hv = *(const float4*)&hrow[wslot][gg * 4];
            float4 mv = *(const float4*)&MT[(lane << 6) + ((gg ^ (lane & 15)) << 2)];
            a0 = fmaf(hv.x, mv.x, a0);
            a1 = fmaf(hv.y, mv.y, a1);
            a2 = fmaf(hv.z, mv.z, a2);
            a3 = fmaf(hv.w, mv.w, a3);
        }
        __builtin_amdgcn_wave_barrier();
        float acc = (a0 + a1) + (a2 + a3);
        vmax = fmaxf(vmax, fmaf(C8, acc, bias));         // undo 8^8 scale (exact 2^24)
    }
    wm[wslot][lane] = vmax;
    __syncthreads();
    if (tid < 64) {
        float m = fmaxf(fmaxf(wm[0][tid], wm[1][tid]), fmaxf(wm[2][tid], wm[3][tid]));
        pmax[blockIdx.x * 64 + tid] = m;
    }
}

__global__ void poolcomb_k(const float* __restrict__ pmax, float* __restrict__ pooled) {
    int i = blockIdx.x * blockDim.x + threadIdx.x;
    if (i >= NGRAPH * 64) return;
    int g = i >> 6, lane = i & 63;
    float m = -INFINITY;
    for (int p = 0; p < PPART; ++p)
        m = fmaxf(m, pmax[(PPART * g + p) * 64 + lane]);
    pooled[i] = m;   // may be -inf for empty graphs; head guards
}

// ---------- head: MLP + BN + out + log_softmax, single block ----------
__global__ __launch_bounds__(256) void head_k(
    const float* __restrict__ pooled,
    const float* __restrict__ m1w, const float* __restrict__ m1b,
    const float* __restrict__ g1, const float* __restrict__ be1,
    const float* __restrict__ m2w, const float* __restrict__ m2b,
    const float* __restrict__ g2, const float* __restrict__ be2,
    const float* __restrict__ ow, const float* __restrict__ ob,
    float* __restrict__ out) {
    __shared__ float A[NGRAPH * 64];
    __shared__ float B[NGRAPH * 64];
    __shared__ float mu[64], rs[64];
    __shared__ float LG[NGRAPH * 10];
    int t = threadIdx.x;
    for (int i = t; i < NGRAPH * 64; i += 256) {
        float f = pooled[i];
        if (!isfinite(f)) f = 0.0f;   // empty-segment guard
        A[i] = f;
    }
    __syncthreads();
    // ---- mlp1 ----
    for (int i = t; i < NGRAPH * 64; i += 256) {
        int g = i >> 6, j = i & 63;
        float acc = m1b[j];
        for (int k = 0; k < 64; ++k) acc = fmaf(A[(g << 6) + k], m1w[k * 64 + j], acc);
        B[i] = acc;
    }
    __syncthreads();
    if (t < 64) {
        float sm = 0.0f, sq = 0.0f;
        for (int g = 0; g < NGRAPH; ++g) { float z = B[g * 64 + t]; sm += z; sq += z * z; }
        float m = sm * (1.0f / NGRAPH);
        float var = sq * (1.0f / NGRAPH) - m * m;
        mu[t] = m; rs[t] = rsqrtf(var + 1e-5f);
    }
    __syncthreads();
    for (int i = t; i < NGRAPH * 64; i += 256) {
        int j = i & 63;
        float z = fmaf((B[i] - mu[j]) * rs[j], g1[j], be1[j]);
        A[i] = fmaxf(z, 0.0f);
    }
    __syncthreads();
    // ---- mlp2 ----
    for (int i = t; i < NGRAPH * 64; i += 256) {
        int g = i >> 6, j = i & 63;
        float acc = m2b[j];
        for (int k = 0; k < 64; ++k) acc = fmaf(A[(g << 6) + k], m2w[k * 64 + j], acc);
        B[i] = acc;
    }
    __syncthreads();
    if (t < 64) {
        float sm = 0.0f, sq = 0.0f;
        for (int g = 0; g < NGRAPH; ++g) { float z = B[g * 64 + t]; sm += z; sq += z * z; }
        float m = sm * (1.0f / NGRAPH);
        float var = sq * (1.0f / NGRAPH) - m * m;
        mu[t] = m; rs[t] = rsqrtf(var + 1e-5f);
    }
    __syncthreads();
    for (int i = t; i < NGRAPH * 64; i += 256) {
        int j = i & 63;
        float z = fmaf((B[i] - mu[j]) * rs[j], g2[j], be2[j]);
        A[i] = fmaxf(z, 0.0f);
    }
    __syncthreads();
    // ---- out + log_softmax ----
    for (int i = t; i < NGRAPH * 10; i += 256) {
        int g = i / 10, j = i - g * 10;
        float acc = ob[j];
        for (int k = 0; k < 64; ++k) acc = fmaf(A[(g << 6) + k], ow[k * 10 + j], acc);
        LG[i] = acc;
    }
    __syncthreads();
    if (t < NGRAPH) {
        float m = -1e30f;
        for (int j = 0; j < 10; ++j) m = fmaxf(m, LG[t * 10 + j]);
        float s = 0.0f;
        for (int j = 0; j < 10; ++j) s += expf(LG[t * 10 + j] - m);
        float lse = m + logf(s);
        for (int j = 0; j < 10; ++j) out[t * 10 + j] = LG[t * 10 + j] - lse;
    }
}

extern "C" void kernel_launch(void* const* d_in, const int* in_sizes, int n_in,
                              void* d_out, int out_size, void* d_ws, size_t ws_size,
                              hipStream_t stream) {
    const float* pos   = (const float*)d_in[0];
    const int*   eidx  = (const int*)d_in[1];
    const int*   batch = (const int*)d_in[2];
    const float* l0w   = (const float*)d_in[3];
    const float* l0b   = (const float*)d_in[4];
    const float* cw    = (const float*)d_in[5];
    const float* l1w   = (const float*)d_in[6];
    const float* l1b   = (const float*)d_in[7];
    const float* m1w   = (const float*)d_in[8];
    const float* m1b   = (const float*)d_in[9];
    const float* g1    = (const float*)d_in[10];
    const float* b1    = (const float*)d_in[11];
    const float* m2w   = (const float*)d_in[12];
    const float* m2b   = (const float*)d_in[13];
    const float* g2    = (const float*)d_in[14];
    const float* b2    = (const float*)d_in[15];
    const float* ow    = (const float*)d_in[16];
    const float* ob    = (const float*)d_in[17];
    float* out = (float*)d_out;
    const int* src = eidx;
    const int* dst = eidx + NEDGES;

    size_t off = 0;
    auto alloc = [&](size_t bytes) -> void* {
        void* p = (char*)d_ws + off;
        off += (bytes + 255) & ~(size_t)255;
        return p;
    };
    float*  x0f    = (float*)alloc((size_t)NNODES * 64 * 4);
    __half* x0h    = (__half*)alloc((size_t)NNODES * 64 * 2);
    __half* xA     = (__half*)alloc((size_t)NNODES * 64 * 2);
    __half* xB     = (__half*)alloc((size_t)NNODES * 64 * 2);
    int*    deg    = (int*)alloc((size_t)NNODES * 4);
    int*    roff   = (int*)alloc((size_t)(NNODES + 1) * 4);
    const int NBLK = (NNODES + 255) / 256;                     // 391
    int*    bsum   = (int*)alloc((size_t)NBLK * 4);
    int*    boff   = (int*)alloc((size_t)NBLK * 4);
    int*    csr    = (int*)alloc((size_t)NEDGES * 4);
    float*  pooled = (float*)alloc((size_t)NGRAPH * 64 * 4);
    float*  pmax   = (float*)alloc((size_t)NGRAPH * PPART * 64 * 4);
    int*    rank   = (int*)xB;   // xB (12.8MB) dead until layer 1 writes it

    hipMemsetAsync(deg, 0, (size_t)NNODES * 4, stream);
    {
        int total = NNODES * 64;
        lin0_k<<<(total + 255) / 256, 256, 0, stream>>>(pos, l0w, l0b, x0f, x0h, total);
    }
    hist_k<<<(NEDGES + 255) / 256, 256, 0, stream>>>(dst, deg, rank, NEDGES);
    scan_part_k<<<NBLK, 256, 0, stream>>>(deg, bsum, NNODES);
    scan_mid_k<<<1, 512, 0, stream>>>(bsum, boff, NBLK, roff, NNODES);
    scan_final_k<<<NBLK, 256, 0, stream>>>(deg, boff, roff, NNODES);
    fill_k<<<(NEDGES + 255) / 256, 256, 0, stream>>>(src, dst, roff, rank, csr, NEDGES);

    const int LBLOCKS = 2048;
    const int TW = LBLOCKS * 256 / 64;   // total waves = 8192
    const __half* cur = x0h;
    for (int l = 0; l < NLAYERS; ++l) {
        float beta    = (float)log(0.5 / (double)(l + 1) + 1.0);
        float x0scale = (float)(0.1 * ldexp(1.0, -3 * l));   // 0.1 / 8^l, exact scale chain
        __half* nxt = (l & 1) ? xB : xA;
        layer_k<<<LBLOCKS, 256, 0, stream>>>(cur, nxt, x0f, cw + (size_t)l * 4096,
                                             roff, csr, beta, x0scale, TW);
        cur = nxt;
    }
    poolpart_k<<<NGRAPH * PPART, 256, 0, stream>>>(cur, l1w, l1b, batch, pmax);
    poolcomb_k<<<(NGRAPH * 64 + 255) / 256, 256, 0, stream>>>(pmax, pooled);
    head_k<<<1, 256, 0, stream>>>(pooled, m1w, m1b, g1, b1, m2w, m2b, g2, b2, ow, ob, out);
}

// Round 14
// 565.726 us; speedup vs baseline: 2.7485x; 1.3608x over previous
//
#include <hip/hip_runtime.h>
#include <math.h>

#define NNODES 100000
#define NEDGES 1200000
#define HD 64
#define NLAYERS 8
#define NGRAPH 100
#define PPART 32          // pooling partitions per graph
#define C8 16777216.0f    // 8^8 = 2^24, exact in f32

typedef _Float16 f16;
typedef __attribute__((ext_vector_type(8))) _Float16 f16x8;
typedef __attribute__((ext_vector_type(4))) float f32x4;

// ---------- lin0: x0 = relu(pos @ lin0_w + lin0_b), f32 + fp16 copies ----------
__global__ void lin0_k(const float* __restrict__ pos, const float* __restrict__ w,
                       const float* __restrict__ b, float* __restrict__ x0f,
                       f16* __restrict__ x0h, int total) {
    int i = blockIdx.x * blockDim.x + threadIdx.x;
    if (i >= total) return;
    int n = i >> 6, h = i & 63;
    float p0 = pos[n * 3 + 0], p1 = pos[n * 3 + 1], p2 = pos[n * 3 + 2];
    float v = fmaf(p0, w[h], fmaf(p1, w[64 + h], fmaf(p2, w[128 + h], b[h])));
    v = fmaxf(v, 0.0f);
    x0f[i] = v;
    x0h[i] = (f16)v;      // layer-0 input, scale c_0 = 1
}

// ---------- CSR build ----------
__global__ void hist_k(const int* __restrict__ dst, int* __restrict__ deg,
                       int* __restrict__ rank, int E) {
    int e = blockIdx.x * blockDim.x + threadIdx.x;
    if (e < E) rank[e] = atomicAdd(&deg[dst[e]], 1);
}

__global__ void scan_part_k(const int* __restrict__ deg, int* __restrict__ bsum, int n) {
    __shared__ int s[256];
    int t = threadIdx.x;
    int i = blockIdx.x * 256 + t;
    s[t] = (i < n) ? deg[i] : 0;
    __syncthreads();
    for (int off = 128; off > 0; off >>= 1) {
        if (t < off) s[t] += s[t + off];
        __syncthreads();
    }
    if (t == 0) bsum[blockIdx.x] = s[0];
}

__global__ void scan_mid_k(const int* __restrict__ bsum, int* __restrict__ boff,
                           int nblk, int* __restrict__ roff, int n) {
    __shared__ int s[512];
    int t = threadIdx.x;
    int v = (t < nblk) ? bsum[t] : 0;
    s[t] = v;
    __syncthreads();
    for (int off = 1; off < 512; off <<= 1) {
        int u = (t >= off) ? s[t - off] : 0;
        __syncthreads();
        s[t] += u;
        __syncthreads();
    }
    if (t < nblk) boff[t] = s[t] - v;          // exclusive
    if (t == nblk - 1) roff[n] = s[t];         // == E
}

__global__ void scan_final_k(const int* __restrict__ deg, const int* __restrict__ boff,
                             int* __restrict__ roff, int n) {
    __shared__ int s[256];
    int t = threadIdx.x;
    int i = blockIdx.x * 256 + t;
    int v = (i < n) ? deg[i] : 0;
    s[t] = v;
    __syncthreads();
    for (int off = 1; off < 256; off <<= 1) {
        int u = (t >= off) ? s[t - off] : 0;
        __syncthreads();
        s[t] += u;
        __syncthreads();
    }
    if (i < n) roff[i] = boff[blockIdx.x] + s[t] - v;   // exclusive scan
}

// pure permute-write, no atomic (rank precomputed in hist_k)
__global__ void fill_k(const int* __restrict__ src, const int* __restrict__ dst,
                       const int* __restrict__ roff, const int* __restrict__ rank,
                       int* __restrict__ csr, int E) {
    int e = blockIdx.x * blockDim.x + threadIdx.x;
    if (e < E) csr[roff[dst[e]] + rank[e]] = src[e];
}

// ---------- prep: pack all 8 layers' folded M into MFMA B-fragment order ----------
// Mfold_l = (1/8) * ((1-beta_l)*I + beta_l*W_l), fp16.
// B-fragment for mfma_f32_16x16x32_f16: lane l holds B[k = 32*kk + 8*(l>>4) + j]
// [col = 16*ct + (l&15)], j=0..7.  Slot t = ((layer*4 + ct)*2 + kk)*64 + lane.
__global__ void prep_k(const float* __restrict__ cw, f16* __restrict__ Bpack) {
    int t = blockIdx.x * blockDim.x + threadIdx.x;
    if (t >= NLAYERS * 4 * 2 * 64) return;
    int layer = t >> 9, rem = t & 511;
    int ct = rem >> 7, kk = (rem >> 6) & 1, lane = rem & 63;
    int g = lane >> 4, r = lane & 15;
    float beta = logf(0.5f / (float)(layer + 1) + 1.0f);
    const float* W = cw + (size_t)layer * 4096;
    f16* outp = Bpack + (size_t)t * 8;
    for (int j = 0; j < 8; ++j) {
        int row = 32 * kk + 8 * g + j;
        int col = 16 * ct + r;
        float m = beta * W[row * 64 + col];
        if (row == col) m += 1.0f - beta;
        outp[j] = (f16)(0.125f * m);
    }
}

// ---------- fused GCN2 layer: gather + residual + MFMA GEMM + relu ----------
// Block = 4 waves = one 16-node tile (grid-stride over 6250 tiles).
// Phase 1: each wave gathers 4 nodes (r9-proven per-node gather; unroll 1 so
//   gather states never interleave -> no spill), h -> fp16 LDS tile (padded
//   rows: 2-way bank access, free).
// Phase 2: wave w = col-tile w: 2x ds_read_b128 A-fragments + 2x
//   mfma_f32_16x16x32_f16 (K=64) + 4 short stores. Matrix pipe does the MLP.
__global__ __launch_bounds__(256, 8) void layer_k(
    const f16* __restrict__ xin, f16* __restrict__ xout,
    const float* __restrict__ x0, const f16* __restrict__ Bp,
    const int* __restrict__ roff, const int* __restrict__ csr,
    float x0scale, int nblocks) {
    __shared__ __align__(16) f16 Htile[16][72];   // 72 = 64 + 8 pad (bank spread)
    const int tid   = threadIdx.x;
    const int lane  = tid & 63;
    const int wslot = tid >> 6;
    // B fragments for this wave's col-tile (held in 8 VGPRs all kernel)
    const f16x8 b0 = *(const f16x8*)(Bp + (size_t)((wslot * 2 + 0) * 64 + lane) * 8);
    const f16x8 b1 = *(const f16x8*)(Bp + (size_t)((wslot * 2 + 1) * 64 + lane) * 8);
    for (int tile = blockIdx.x; tile < NNODES / 16; tile += nblocks) {
        const int nbase = tile << 4;
#pragma unroll 1
        for (int i = 0; i < 4; ++i) {
            const int n = nbase + (wslot << 2) + i;
            const int beg = roff[n], end = roff[n + 1];
            float x0v = x0[(n << 6) + lane];
            float s0 = 0.0f, s1 = 0.0f, s2 = 0.0f, s3 = 0.0f;
            int e = beg;
            for (; e + 8 <= end; e += 8) {
                int e0 = csr[e + 0], e1 = csr[e + 1], e2 = csr[e + 2], e3 = csr[e + 3];
                int e4 = csr[e + 4], e5 = csr[e + 5], e6 = csr[e + 6], e7 = csr[e + 7];
                f16 a0 = xin[(e0 << 6) + lane];
                f16 a1 = xin[(e1 << 6) + lane];
                f16 a2 = xin[(e2 << 6) + lane];
                f16 a3 = xin[(e3 << 6) + lane];
                f16 a4 = xin[(e4 << 6) + lane];
                f16 a5 = xin[(e5 << 6) + lane];
                f16 a6 = xin[(e6 << 6) + lane];
                f16 a7 = xin[(e7 << 6) + lane];
                s0 += (float)a0; s1 += (float)a1; s2 += (float)a2; s3 += (float)a3;
                s0 += (float)a4; s1 += (float)a5; s2 += (float)a6; s3 += (float)a7;
            }
            for (; e + 4 <= end; e += 4) {
                int e0 = csr[e + 0], e1 = csr[e + 1], e2 = csr[e + 2], e3 = csr[e + 3];
                s0 += (float)xin[(e0 << 6) + lane];
                s1 += (float)xin[(e1 << 6) + lane];
                s2 += (float)xin[(e2 << 6) + lane];
                s3 += (float)xin[(e3 << 6) + lane];
            }
            for (; e < end; ++e) s0 += (float)xin[(csr[e] << 6) + lane];
            float h = fmaf(0.9f, (s0 + s1) + (s2 + s3), x0scale * x0v);
            Htile[(wslot << 2) + i][lane] = (f16)h;
        }
        __syncthreads();
        // A fragments: lane l -> row (l&15), k = 8*(l>>4) + {0..7} (+32 for kk=1)
        const int ar = lane & 15, ag = lane >> 4;
        f16x8 a0 = *(const f16x8*)&Htile[ar][(ag << 3) + 0];
        f16x8 a1 = *(const f16x8*)&Htile[ar][(ag << 3) + 32];
        f32x4 acc = {0.0f, 0.0f, 0.0f, 0.0f};
        acc = __builtin_amdgcn_mfma_f32_16x16x32_f16(a0, b0, acc, 0, 0, 0);
        acc = __builtin_amdgcn_mfma_f32_16x16x32_f16(a1, b1, acc, 0, 0, 0);
        // D: col = lane&15, row = (lane>>4)*4 + reg
        const int col = (wslot << 4) + ar;
        const int rbase = nbase + (ag << 2);
#pragma unroll
        for (int j = 0; j < 4; ++j) {
            xout[((rbase + j) << 6) + col] = (f16)fmaxf(acc[j], 0.0f);
        }
        __syncthreads();   // protect Htile before next tile's writes
    }
}

// ---------- lin1 + segment_max pooling, ZERO atomics, 32 partitions ----------
__device__ __forceinline__ int lbound(const int* __restrict__ a, int n, int v) {
    int lo = 0, hi = n;
    while (lo < hi) { int mid = (lo + hi) >> 1; if (a[mid] < v) lo = mid + 1; else hi = mid; }
    return lo;
}

__global__ __launch_bounds__(256, 8) void poolpart_k(
    const f16* __restrict__ xin, const float* __restrict__ W,
    const float* __restrict__ bvec, const int* __restrict__ batch,
    float* __restrict__ pmax) {
    __shared__ __align__(16) float MT[64 * 64];
    __shared__ __align__(16) float hrow[4][64];
    __shared__ float wm[4][64];
    const int tid   = threadIdx.x;
    const int lane  = tid & 63;
    const int wslot = tid >> 6;
    for (int idx = tid; idx < 4096; idx += 256) {
        int k = idx >> 6, j = idx & 63;
        MT[j * 64 + (((k >> 2) ^ (j & 15)) << 2) + (k & 3)] = W[idx];
    }
    __syncthreads();
    const int g = blockIdx.x / PPART, part = blockIdx.x % PPART;
    const int lo = lbound(batch, NNODES, g);
    const int hi = lbound(batch, NNODES, g + 1);
    const int cnt = hi - lo;
    const int qlo = lo + (cnt * part) / PPART;
    const int qhi = lo + (cnt * (part + 1)) / PPART;
    const float bias = bvec[lane];
    float vmax = -INFINITY;
    for (int n = qlo + wslot; n < qhi; n += 4) {
        hrow[wslot][lane] = (float)xin[(n << 6) + lane];   // stored units (x/8^8)
        __builtin_amdgcn_wave_barrier();
        float a0 = 0.0f, a1 = 0.0f, a2 = 0.0f, a3 = 0.0f;
#pragma unroll
        for (int gg = 0; gg < 16; ++gg) {
            float4 hv = *(const float4*)&hrow[wslot][gg * 4];
            float4 mv = *(const float4*)&MT[(lane << 6) + ((gg ^ (lane & 15)) << 2)];
            a0 = fmaf(hv.x, mv.x, a0);
            a1 = fmaf(hv.y, mv.y, a1);
            a2 = fmaf(hv.z, mv.z, a2);
            a3 = fmaf(hv.w, mv.w, a3);
        }
        __builtin_amdgcn_wave_barrier();
        float acc = (a0 + a1) + (a2 + a3);
        vmax = fmaxf(vmax, fmaf(C8, acc, bias));         // undo 8^8 scale (exact 2^24)
    }
    wm[wslot][lane] = vmax;
    __syncthreads();
    if (tid < 64) {
        float m = fmaxf(fmaxf(wm[0][tid], wm[1][tid]), fmaxf(wm[2][tid], wm[3][tid]));
        pmax[blockIdx.x * 64 + tid] = m;
    }
}

__global__ void poolcomb_k(const float* __restrict__ pmax, float* __restrict__ pooled) {
    int i = blockIdx.x * blockDim.x + threadIdx.x;
    if (i >= NGRAPH * 64) return;
    int g = i >> 6, lane = i & 63;
    float m = -INFINITY;
    for (int p = 0; p < PPART; ++p)
        m = fmaxf(m, pmax[(PPART * g + p) * 64 + lane]);
    pooled[i] = m;   // may be -inf for empty graphs; head guards
}

// ---------- head: MLP + BN + out + log_softmax, single block ----------
__global__ __launch_bounds__(256) void head_k(
    const float* __restrict__ pooled,
    const float* __restrict__ m1w, const float* __restrict__ m1b,
    const float* __restrict__ g1, const float* __restrict__ be1,
    const float* __restrict__ m2w, const float* __restrict__ m2b,
    const float* __restrict__ g2, const float* __restrict__ be2,
    const float* __restrict__ ow, const float* __restrict__ ob,
    float* __restrict__ out) {
    __shared__ float A[NGRAPH * 64];
    __shared__ float B[NGRAPH * 64];
    __shared__ float mu[64], rs[64];
    __shared__ float LG[NGRAPH * 10];
    int t = threadIdx.x;
    for (int i = t; i < NGRAPH * 64; i += 256) {
        float f = pooled[i];
        if (!isfinite(f)) f = 0.0f;   // empty-segment guard
        A[i] = f;
    }
    __syncthreads();
    // ---- mlp1 ----
    for (int i = t; i < NGRAPH * 64; i += 256) {
        int g = i >> 6, j = i & 63;
        float acc = m1b[j];
        for (int k = 0; k < 64; ++k) acc = fmaf(A[(g << 6) + k], m1w[k * 64 + j], acc);
        B[i] = acc;
    }
    __syncthreads();
    if (t < 64) {
        float sm = 0.0f, sq = 0.0f;
        for (int g = 0; g < NGRAPH; ++g) { float z = B[g * 64 + t]; sm += z; sq += z * z; }
        float m = sm * (1.0f / NGRAPH);
        float var = sq * (1.0f / NGRAPH) - m * m;
        mu[t] = m; rs[t] = rsqrtf(var + 1e-5f);
    }
    __syncthreads();
    for (int i = t; i < NGRAPH * 64; i += 256) {
        int j = i & 63;
        float z = fmaf((B[i] - mu[j]) * rs[j], g1[j], be1[j]);
        A[i] = fmaxf(z, 0.0f);
    }
    __syncthreads();
    // ---- mlp2 ----
    for (int i = t; i < NGRAPH * 64; i += 256) {
        int g = i >> 6, j = i & 63;
        float acc = m2b[j];
        for (int k = 0; k < 64; ++k) acc = fmaf(A[(g << 6) + k], m2w[k * 64 + j], acc);
        B[i] = acc;
    }
    __syncthreads();
    if (t < 64) {
        float sm = 0.0f, sq = 0.0f;
        for (int g = 0; g < NGRAPH; ++g) { float z = B[g * 64 + t]; sm += z; sq += z * z; }
        float m = sm * (1.0f / NGRAPH);
        float var = sq * (1.0f / NGRAPH) - m * m;
        mu[t] = m; rs[t] = rsqrtf(var + 1e-5f);
    }
    __syncthreads();
    for (int i = t; i < NGRAPH * 64; i += 256) {
        int j = i & 63;
        float z = fmaf((B[i] - mu[j]) * rs[j], g2[j], be2[j]);
        A[i] = fmaxf(z, 0.0f);
    }
    __syncthreads();
    // ---- out + log_softmax ----
    for (int i = t; i < NGRAPH * 10; i += 256) {
        int g = i / 10, j = i - g * 10;
        float acc = ob[j];
        for (int k = 0; k < 64; ++k) acc = fmaf(A[(g << 6) + k], ow[k * 10 + j], acc);
        LG[i] = acc;
    }
    __syncthreads();
    if (t < NGRAPH) {
        float m = -1e30f;
        for (int j = 0; j < 10; ++j) m = fmaxf(m, LG[t * 10 + j]);
        float s = 0.0f;
        for (int j = 0; j < 10; ++j) s += expf(LG[t * 10 + j] - m);
        float lse = m + logf(s);
        for (int j = 0; j < 10; ++j) out[t * 10 + j] = LG[t * 10 + j] - lse;
    }
}

extern "C" void kernel_launch(void* const* d_in, const int* in_sizes, int n_in,
                              void* d_out, int out_size, void* d_ws, size_t ws_size,
                              hipStream_t stream) {
    const float* pos   = (const float*)d_in[0];
    const int*   eidx  = (const int*)d_in[1];
    const int*   batch = (const int*)d_in[2];
    const float* l0w   = (const float*)d_in[3];
    const float* l0b   = (const float*)d_in[4];
    const float* cw    = (const float*)d_in[5];
    const float* l1w   = (const float*)d_in[6];
    const float* l1b   = (const float*)d_in[7];
    const float* m1w   = (const float*)d_in[8];
    const float* m1b   = (const float*)d_in[9];
    const float* g1    = (const float*)d_in[10];
    const float* b1    = (const float*)d_in[11];
    const float* m2w   = (const float*)d_in[12];
    const float* m2b   = (const float*)d_in[13];
    const float* g2    = (const float*)d_in[14];
    const float* b2    = (const float*)d_in[15];
    const float* ow    = (const float*)d_in[16];
    const float* ob    = (const float*)d_in[17];
    float* out = (float*)d_out;
    const int* src = eidx;
    const int* dst = eidx + NEDGES;

    size_t off = 0;
    auto alloc = [&](size_t bytes) -> void* {
        void* p = (char*)d_ws + off;
        off += (bytes + 255) & ~(size_t)255;
        return p;
    };
    float* x0f    = (float*)alloc((size_t)NNODES * 64 * 4);
    f16*   x0h    = (f16*)alloc((size_t)NNODES * 64 * 2);
    f16*   xA     = (f16*)alloc((size_t)NNODES * 64 * 2);
    f16*   xB     = (f16*)alloc((size_t)NNODES * 64 * 2);
    int*   deg    = (int*)alloc((size_t)NNODES * 4);
    int*   roff   = (int*)alloc((size_t)(NNODES + 1) * 4);
    const int NBLK = (NNODES + 255) / 256;                     // 391
    int*   bsum   = (int*)alloc((size_t)NBLK * 4);
    int*   boff   = (int*)alloc((size_t)NBLK * 4);
    int*   csr    = (int*)alloc((size_t)NEDGES * 4);
    float* pooled = (float*)alloc((size_t)NGRAPH * 64 * 4);
    float* pmax   = (float*)alloc((size_t)NGRAPH * PPART * 64 * 4);
    f16*   Bpack  = (f16*)alloc((size_t)NLAYERS * 4 * 2 * 64 * 8 * 2);   // 64KB
    int*   rank   = (int*)xB;   // xB dead until layer 1 writes it

    hipMemsetAsync(deg, 0, (size_t)NNODES * 4, stream);
    {
        int total = NNODES * 64;
        lin0_k<<<(total + 255) / 256, 256, 0, stream>>>(pos, l0w, l0b, x0f, x0h, total);
    }
    hist_k<<<(NEDGES + 255) / 256, 256, 0, stream>>>(dst, deg, rank, NEDGES);
    scan_part_k<<<NBLK, 256, 0, stream>>>(deg, bsum, NNODES);
    scan_mid_k<<<1, 512, 0, stream>>>(bsum, boff, NBLK, roff, NNODES);
    scan_final_k<<<NBLK, 256, 0, stream>>>(deg, boff, roff, NNODES);
    fill_k<<<(NEDGES + 255) / 256, 256, 0, stream>>>(src, dst, roff, rank, csr, NEDGES);
    prep_k<<<(NLAYERS * 4 * 2 * 64 + 255) / 256, 256, 0, stream>>>(cw, Bpack);

    const int LBLOCKS = 2048;
    const f16* cur = x0h;
    for (int l = 0; l < NLAYERS; ++l) {
        float x0scale = (float)(0.1 * ldexp(1.0, -3 * l));   // 0.1 / 8^l
        f16* nxt = (l & 1) ? xB : xA;
        layer_k<<<LBLOCKS, 256, 0, stream>>>(cur, nxt, x0f,
                                             Bpack + (size_t)l * 4 * 2 * 64 * 8,
                                             roff, csr, x0scale, LBLOCKS);
        cur = nxt;
    }
    poolpart_k<<<NGRAPH * PPART, 256, 0, stream>>>(cur, l1w, l1b, batch, pmax);
    poolcomb_k<<<(NGRAPH * 64 + 255) / 256, 256, 0, stream>>>(pmax, pooled);
    head_k<<<1, 256, 0, stream>>>(pooled, m1w, m1b, g1, b1, m2w, m2b, g2, b2, ow, ob, out);
}

// Round 15
// 545.706 us; speedup vs baseline: 2.8493x; 1.0367x over previous
//
#include <hip/hip_runtime.h>
#include <math.h>

#define NNODES 100000
#define NEDGES 1200000
#define HD 64
#define NLAYERS 8
#define NGRAPH 100
#define PPART 32          // pooling partitions per graph
#define C8 16777216.0f    // 8^8 = 2^24, exact in f32

typedef _Float16 f16;
typedef __attribute__((ext_vector_type(8))) _Float16 f16x8;
typedef __attribute__((ext_vector_type(4))) float f32x4;

// ---------- lin0: x0 = relu(pos @ lin0_w + lin0_b), fp16 (scale c_0 = 1) ----------
__global__ void lin0_k(const float* __restrict__ pos, const float* __restrict__ w,
                       const float* __restrict__ b, f16* __restrict__ x0h, int total) {
    int i = blockIdx.x * blockDim.x + threadIdx.x;
    if (i >= total) return;
    int n = i >> 6, h = i & 63;
    float p0 = pos[n * 3 + 0], p1 = pos[n * 3 + 1], p2 = pos[n * 3 + 2];
    float v = fmaf(p0, w[h], fmaf(p1, w[64 + h], fmaf(p2, w[128 + h], b[h])));
    x0h[i] = (f16)fmaxf(v, 0.0f);
}

// ---------- CSR build ----------
__global__ void hist_k(const int* __restrict__ dst, int* __restrict__ deg,
                       int* __restrict__ rank, int E) {
    int e = blockIdx.x * blockDim.x + threadIdx.x;
    if (e < E) rank[e] = atomicAdd(&deg[dst[e]], 1);
}

__global__ void scan_part_k(const int* __restrict__ deg, int* __restrict__ bsum, int n) {
    __shared__ int s[256];
    int t = threadIdx.x;
    int i = blockIdx.x * 256 + t;
    s[t] = (i < n) ? deg[i] : 0;
    __syncthreads();
    for (int off = 128; off > 0; off >>= 1) {
        if (t < off) s[t] += s[t + off];
        __syncthreads();
    }
    if (t == 0) bsum[blockIdx.x] = s[0];
}

__global__ void scan_mid_k(const int* __restrict__ bsum, int* __restrict__ boff,
                           int nblk, int* __restrict__ roff, int n) {
    __shared__ int s[512];
    int t = threadIdx.x;
    int v = (t < nblk) ? bsum[t] : 0;
    s[t] = v;
    __syncthreads();
    for (int off = 1; off < 512; off <<= 1) {
        int u = (t >= off) ? s[t - off] : 0;
        __syncthreads();
        s[t] += u;
        __syncthreads();
    }
    if (t < nblk) boff[t] = s[t] - v;          // exclusive
    if (t == nblk - 1) roff[n] = s[t];         // == E
}

__global__ void scan_final_k(const int* __restrict__ deg, const int* __restrict__ boff,
                             int* __restrict__ roff, int n) {
    __shared__ int s[256];
    int t = threadIdx.x;
    int i = blockIdx.x * 256 + t;
    int v = (i < n) ? deg[i] : 0;
    s[t] = v;
    __syncthreads();
    for (int off = 1; off < 256; off <<= 1) {
        int u = (t >= off) ? s[t - off] : 0;
        __syncthreads();
        s[t] += u;
        __syncthreads();
    }
    if (i < n) roff[i] = boff[blockIdx.x] + s[t] - v;   // exclusive scan
}

// pure permute-write, no atomic (rank precomputed in hist_k)
__global__ void fill_k(const int* __restrict__ src, const int* __restrict__ dst,
                       const int* __restrict__ roff, const int* __restrict__ rank,
                       int* __restrict__ csr, int E) {
    int e = blockIdx.x * blockDim.x + threadIdx.x;
    if (e < E) csr[roff[dst[e]] + rank[e]] = src[e];
}

// ---------- prep: pack 9 matrices into MFMA B-fragment order ----------
// mat 0..7: Mfold_l = (1/8)*((1-beta_l)*I + beta_l*W_l)   (layer GEMMs)
// mat 8:    l1w raw                                        (lin1 GEMM)
// B-fragment (mfma_f32_16x16x32_f16): lane l holds B[k=32*kk+8*(l>>4)+j]
// [col=16*ct+(l&15)], j=0..7.  Slot t = ((mat*4 + ct)*2 + kk)*64 + lane.
__global__ void prep_k(const float* __restrict__ cw, const float* __restrict__ l1w,
                       f16* __restrict__ Bpack) {
    int t = blockIdx.x * blockDim.x + threadIdx.x;
    if (t >= 9 * 4 * 2 * 64) return;
    int mat = t >> 9, rem = t & 511;
    int ct = rem >> 7, kk = (rem >> 6) & 1, lane = rem & 63;
    int g = lane >> 4, r = lane & 15;
    f16* outp = Bpack + (size_t)t * 8;
    if (mat < 8) {
        float beta = logf(0.5f / (float)(mat + 1) + 1.0f);
        const float* W = cw + (size_t)mat * 4096;
        for (int j = 0; j < 8; ++j) {
            int row = 32 * kk + 8 * g + j;
            int col = 16 * ct + r;
            float m = beta * W[row * 64 + col];
            if (row == col) m += 1.0f - beta;
            outp[j] = (f16)(0.125f * m);
        }
    } else {
        for (int j = 0; j < 8; ++j) {
            int row = 32 * kk + 8 * g + j;
            int col = 16 * ct + r;
            outp[j] = (f16)l1w[row * 64 + col];
        }
    }
}

// ---------- fused GCN2 layer: gather + residual + MFMA GEMM + relu ----------
// Block = 4 waves = one 16-node tile (grid-stride). Phase 1: gather 4 nodes
// per wave (unroll 1: gather states never interleave -> no spill), h -> fp16
// LDS tile. Phase 2: wave w = col-tile w: 2x ds_read_b128 A-frags + 2x MFMA.
// x0 residual read as fp16 (0.1-weighted term; adds ~2^-11 rel, negligible).
__global__ __launch_bounds__(256, 8) void layer_k(
    const f16* __restrict__ xin, f16* __restrict__ xout,
    const f16* __restrict__ x0, const f16* __restrict__ Bp,
    const int* __restrict__ roff, const int* __restrict__ csr,
    float x0scale, int nblocks) {
    __shared__ __align__(16) f16 Htile[16][72];   // 72 = 64 + 8 pad
    const int tid   = threadIdx.x;
    const int lane  = tid & 63;
    const int wslot = tid >> 6;
    const f16x8 b0 = *(const f16x8*)(Bp + (size_t)((wslot * 2 + 0) * 64 + lane) * 8);
    const f16x8 b1 = *(const f16x8*)(Bp + (size_t)((wslot * 2 + 1) * 64 + lane) * 8);
    for (int tile = blockIdx.x; tile < NNODES / 16; tile += nblocks) {
        const int nbase = tile << 4;
#pragma unroll 1
        for (int i = 0; i < 4; ++i) {
            const int n = nbase + (wslot << 2) + i;
            const int beg = roff[n], end = roff[n + 1];
            float x0v = (float)x0[(n << 6) + lane];
            float s0 = 0.0f, s1 = 0.0f, s2 = 0.0f, s3 = 0.0f;
            int e = beg;
            for (; e + 8 <= end; e += 8) {
                int e0 = csr[e + 0], e1 = csr[e + 1], e2 = csr[e + 2], e3 = csr[e + 3];
                int e4 = csr[e + 4], e5 = csr[e + 5], e6 = csr[e + 6], e7 = csr[e + 7];
                f16 a0 = xin[(e0 << 6) + lane];
                f16 a1 = xin[(e1 << 6) + lane];
                f16 a2 = xin[(e2 << 6) + lane];
                f16 a3 = xin[(e3 << 6) + lane];
                f16 a4 = xin[(e4 << 6) + lane];
                f16 a5 = xin[(e5 << 6) + lane];
                f16 a6 = xin[(e6 << 6) + lane];
                f16 a7 = xin[(e7 << 6) + lane];
                s0 += (float)a0; s1 += (float)a1; s2 += (float)a2; s3 += (float)a3;
                s0 += (float)a4; s1 += (float)a5; s2 += (float)a6; s3 += (float)a7;
            }
            for (; e + 4 <= end; e += 4) {
                int e0 = csr[e + 0], e1 = csr[e + 1], e2 = csr[e + 2], e3 = csr[e + 3];
                s0 += (float)xin[(e0 << 6) + lane];
                s1 += (float)xin[(e1 << 6) + lane];
                s2 += (float)xin[(e2 << 6) + lane];
                s3 += (float)xin[(e3 << 6) + lane];
            }
            for (; e < end; ++e) s0 += (float)xin[(csr[e] << 6) + lane];
            float h = fmaf(0.9f, (s0 + s1) + (s2 + s3), x0scale * x0v);
            Htile[(wslot << 2) + i][lane] = (f16)h;
        }
        __syncthreads();
        const int ar = lane & 15, ag = lane >> 4;
        f16x8 a0 = *(const f16x8*)&Htile[ar][(ag << 3) + 0];
        f16x8 a1 = *(const f16x8*)&Htile[ar][(ag << 3) + 32];
        f32x4 acc = {0.0f, 0.0f, 0.0f, 0.0f};
        acc = __builtin_amdgcn_mfma_f32_16x16x32_f16(a0, b0, acc, 0, 0, 0);
        acc = __builtin_amdgcn_mfma_f32_16x16x32_f16(a1, b1, acc, 0, 0, 0);
        const int col = (wslot << 4) + ar;
        const int rbase = nbase + (ag << 2);
#pragma unroll
        for (int j = 0; j < 4; ++j) {
            xout[((rbase + j) << 6) + col] = (f16)fmaxf(acc[j], 0.0f);
        }
        __syncthreads();
    }
}

// ---------- lin1 as pure MFMA GEMM (no gather, A-frags direct from global) ----------
__global__ __launch_bounds__(256, 8) void lin1_k(
    const f16* __restrict__ xin, f16* __restrict__ yout,
    const f16* __restrict__ Bp, int nblocks) {
    const int lane  = threadIdx.x & 63;
    const int wslot = threadIdx.x >> 6;
    const f16x8 b0 = *(const f16x8*)(Bp + (size_t)((wslot * 2 + 0) * 64 + lane) * 8);
    const f16x8 b1 = *(const f16x8*)(Bp + (size_t)((wslot * 2 + 1) * 64 + lane) * 8);
    const int ar = lane & 15, ag = lane >> 4;
    for (int tile = blockIdx.x; tile < NNODES / 16; tile += nblocks) {
        const int nbase = tile << 4;
        f16x8 a0 = *(const f16x8*)(xin + ((size_t)(nbase + ar) << 6) + (ag << 3));
        f16x8 a1 = *(const f16x8*)(xin + ((size_t)(nbase + ar) << 6) + (ag << 3) + 32);
        f32x4 acc = {0.0f, 0.0f, 0.0f, 0.0f};
        acc = __builtin_amdgcn_mfma_f32_16x16x32_f16(a0, b0, acc, 0, 0, 0);
        acc = __builtin_amdgcn_mfma_f32_16x16x32_f16(a1, b1, acc, 0, 0, 0);
        const int col = (wslot << 4) + ar;
        const int rbase = nbase + (ag << 2);
#pragma unroll
        for (int j = 0; j < 4; ++j) {
            yout[((rbase + j) << 6) + col] = (f16)acc[j];   // stored units
        }
    }
}

// ---------- segment max over lin1 output (pure fp16 row-max) ----------
__device__ __forceinline__ int lbound(const int* __restrict__ a, int n, int v) {
    int lo = 0, hi = n;
    while (lo < hi) { int mid = (lo + hi) >> 1; if (a[mid] < v) lo = mid + 1; else hi = mid; }
    return lo;
}

__global__ __launch_bounds__(256, 8) void segmax_k(
    const f16* __restrict__ y, const int* __restrict__ batch,
    float* __restrict__ pmax) {
    __shared__ float wm[4][64];
    const int tid   = threadIdx.x;
    const int lane  = tid & 63;
    const int wslot = tid >> 6;
    const int g = blockIdx.x / PPART, part = blockIdx.x % PPART;
    const int lo = lbound(batch, NNODES, g);
    const int hi = lbound(batch, NNODES, g + 1);
    const int cnt = hi - lo;
    const int qlo = lo + (cnt * part) / PPART;
    const int qhi = lo + (cnt * (part + 1)) / PPART;
    float vmax = -INFINITY;
    for (int n = qlo + wslot; n < qhi; n += 4)
        vmax = fmaxf(vmax, (float)y[(n << 6) + lane]);
    wm[wslot][lane] = vmax;
    __syncthreads();
    if (tid < 64) {
        float m = fmaxf(fmaxf(wm[0][tid], wm[1][tid]), fmaxf(wm[2][tid], wm[3][tid]));
        pmax[blockIdx.x * 64 + tid] = m;
    }
}

// combine partitions + undo 8^8 scale + add bias (max commutes with affine)
__global__ void poolcomb_k(const float* __restrict__ pmax,
                           const float* __restrict__ bvec,
                           float* __restrict__ pooled) {
    int i = blockIdx.x * blockDim.x + threadIdx.x;
    if (i >= NGRAPH * 64) return;
    int g = i >> 6, lane = i & 63;
    float m = -INFINITY;
    for (int p = 0; p < PPART; ++p)
        m = fmaxf(m, pmax[(PPART * g + p) * 64 + lane]);
    pooled[i] = fmaf(C8, m, bvec[lane]);   // -inf stays -inf; head guards
}

// ---------- head: MLP + BN + out + log_softmax, single block ----------
__global__ __launch_bounds__(256) void head_k(
    const float* __restrict__ pooled,
    const float* __restrict__ m1w, const float* __restrict__ m1b,
    const float* __restrict__ g1, const float* __restrict__ be1,
    const float* __restrict__ m2w, const float* __restrict__ m2b,
    const float* __restrict__ g2, const float* __restrict__ be2,
    const float* __restrict__ ow, const float* __restrict__ ob,
    float* __restrict__ out) {
    __shared__ float A[NGRAPH * 64];
    __shared__ float B[NGRAPH * 64];
    __shared__ float mu[64], rs[64];
    __shared__ float LG[NGRAPH * 10];
    int t = threadIdx.x;
    for (int i = t; i < NGRAPH * 64; i += 256) {
        float f = pooled[i];
        if (!isfinite(f)) f = 0.0f;   // empty-segment guard
        A[i] = f;
    }
    __syncthreads();
    // ---- mlp1 ----
    for (int i = t; i < NGRAPH * 64; i += 256) {
        int g = i >> 6, j = i & 63;
        float acc = m1b[j];
        for (int k = 0; k < 64; ++k) acc = fmaf(A[(g << 6) + k], m1w[k * 64 + j], acc);
        B[i] = acc;
    }
    __syncthreads();
    if (t < 64) {
        float sm = 0.0f, sq = 0.0f;
        for (int g = 0; g < NGRAPH; ++g) { float z = B[g * 64 + t]; sm += z; sq += z * z; }
        float m = sm * (1.0f / NGRAPH);
        float var = sq * (1.0f / NGRAPH) - m * m;
        mu[t] = m; rs[t] = rsqrtf(var + 1e-5f);
    }
    __syncthreads();
    for (int i = t; i < NGRAPH * 64; i += 256) {
        int j = i & 63;
        float z = fmaf((B[i] - mu[j]) * rs[j], g1[j], be1[j]);
        A[i] = fmaxf(z, 0.0f);
    }
    __syncthreads();
    // ---- mlp2 ----
    for (int i = t; i < NGRAPH * 64; i += 256) {
        int g = i >> 6, j = i & 63;
        float acc = m2b[j];
        for (int k = 0; k < 64; ++k) acc = fmaf(A[(g << 6) + k], m2w[k * 64 + j], acc);
        B[i] = acc;
    }
    __syncthreads();
    if (t < 64) {
        float sm = 0.0f, sq = 0.0f;
        for (int g = 0; g < NGRAPH; ++g) { float z = B[g * 64 + t]; sm += z; sq += z * z; }
        float m = sm * (1.0f / NGRAPH);
        float var = sq * (1.0f / NGRAPH) - m * m;
        mu[t] = m; rs[t] = rsqrtf(var + 1e-5f);
    }
    __syncthreads();
    for (int i = t; i < NGRAPH * 64; i += 256) {
        int j = i & 63;
        float z = fmaf((B[i] - mu[j]) * rs[j], g2[j], be2[j]);
        A[i] = fmaxf(z, 0.0f);
    }
    __syncthreads();
    // ---- out + log_softmax ----
    for (int i = t; i < NGRAPH * 10; i += 256) {
        int g = i / 10, j = i - g * 10;
        float acc = ob[j];
        for (int k = 0; k < 64; ++k) acc = fmaf(A[(g << 6) + k], ow[k * 10 + j], acc);
        LG[i] = acc;
    }
    __syncthreads();
    if (t < NGRAPH) {
        float m = -1e30f;
        for (int j = 0; j < 10; ++j) m = fmaxf(m, LG[t * 10 + j]);
        float s = 0.0f;
        for (int j = 0; j < 10; ++j) s += expf(LG[t * 10 + j] - m);
        float lse = m + logf(s);
        for (int j = 0; j < 10; ++j) out[t * 10 + j] = LG[t * 10 + j] - lse;
    }
}

extern "C" void kernel_launch(void* const* d_in, const int* in_sizes, int n_in,
                              void* d_out, int out_size, void* d_ws, size_t ws_size,
                              hipStream_t stream) {
    const float* pos   = (const float*)d_in[0];
    const int*   eidx  = (const int*)d_in[1];
    const int*   batch = (const int*)d_in[2];
    const float* l0w   = (const float*)d_in[3];
    const float* l0b   = (const float*)d_in[4];
    const float* cw    = (const float*)d_in[5];
    const float* l1w   = (const float*)d_in[6];
    const float* l1b   = (const float*)d_in[7];
    const float* m1w   = (const float*)d_in[8];
    const float* m1b   = (const float*)d_in[9];
    const float* g1    = (const float*)d_in[10];
    const float* b1    = (const float*)d_in[11];
    const float* m2w   = (const float*)d_in[12];
    const float* m2b   = (const float*)d_in[13];
    const float* g2    = (const float*)d_in[14];
    const float* b2    = (const float*)d_in[15];
    const float* ow    = (const float*)d_in[16];
    const float* ob    = (const float*)d_in[17];
    float* out = (float*)d_out;
    const int* src = eidx;
    const int* dst = eidx + NEDGES;

    size_t off = 0;
    auto alloc = [&](size_t bytes) -> void* {
        void* p = (char*)d_ws + off;
        off += (bytes + 255) & ~(size_t)255;
        return p;
    };
    f16*   x0h    = (f16*)alloc((size_t)NNODES * 64 * 2);
    f16*   xA     = (f16*)alloc((size_t)NNODES * 64 * 2);
    f16*   xB     = (f16*)alloc((size_t)NNODES * 64 * 2);
    int*   deg    = (int*)alloc((size_t)NNODES * 4);
    int*   roff   = (int*)alloc((size_t)(NNODES + 1) * 4);
    const int NBLK = (NNODES + 255) / 256;                     // 391
    int*   bsum   = (int*)alloc((size_t)NBLK * 4);
    int*   boff   = (int*)alloc((size_t)NBLK * 4);
    int*   csr    = (int*)alloc((size_t)NEDGES * 4);
    float* pooled = (float*)alloc((size_t)NGRAPH * 64 * 4);
    float* pmax   = (float*)alloc((size_t)NGRAPH * PPART * 64 * 4);
    f16*   Bpack  = (f16*)alloc((size_t)9 * 4 * 2 * 64 * 8 * 2);   // 72KB
    int*   rank   = (int*)xB;   // xB dead until layer 1 writes it

    hipMemsetAsync(deg, 0, (size_t)NNODES * 4, stream);
    {
        int total = NNODES * 64;
        lin0_k<<<(total + 255) / 256, 256, 0, stream>>>(pos, l0w, l0b, x0h, total);
    }
    hist_k<<<(NEDGES + 255) / 256, 256, 0, stream>>>(dst, deg, rank, NEDGES);
    scan_part_k<<<NBLK, 256, 0, stream>>>(deg, bsum, NNODES);
    scan_mid_k<<<1, 512, 0, stream>>>(bsum, boff, NBLK, roff, NNODES);
    scan_final_k<<<NBLK, 256, 0, stream>>>(deg, boff, roff, NNODES);
    fill_k<<<(NEDGES + 255) / 256, 256, 0, stream>>>(src, dst, roff, rank, csr, NEDGES);
    prep_k<<<(9 * 4 * 2 * 64 + 255) / 256, 256, 0, stream>>>(cw, l1w, Bpack);

    const int LBLOCKS = 2048;
    const f16* cur = x0h;
    for (int l = 0; l < NLAYERS; ++l) {
        float x0scale = (float)(0.1 * ldexp(1.0, -3 * l));   // 0.1 / 8^l
        f16* nxt = (l & 1) ? xB : xA;
        layer_k<<<LBLOCKS, 256, 0, stream>>>(cur, nxt, x0h,
                                             Bpack + (size_t)l * 4 * 2 * 64 * 8,
                                             roff, csr, x0scale, LBLOCKS);
        cur = nxt;
    }
    // lin1 into the free buffer (cur == xB after 8 layers; xA is dead)
    f16* l1out = (cur == xA) ? xB : xA;
    lin1_k<<<LBLOCKS, 256, 0, stream>>>(cur, l1out,
                                        Bpack + (size_t)8 * 4 * 2 * 64 * 8, LBLOCKS);
    segmax_k<<<NGRAPH * PPART, 256, 0, stream>>>(l1out, batch, pmax);
    poolcomb_k<<<(NGRAPH * 64 + 255) / 256, 256, 0, stream>>>(pmax, l1b, pooled);
    head_k<<<1, 256, 0, stream>>>(pooled, m1w, m1b, g1, b1, m2w, m2b, g2, b2, ow, ob, out);
}